// Round 7
// baseline (3356.013 us; speedup 1.0000x reference)
//
#include <hip/hip_runtime.h>

// ---------------------------------------------------------------------------
// 2-layer ReLU RNN (B=64,T=512,I=256,H=512) + FC(512->1) + sigmoid. fp32 I/O.
// Scan: fp16 MFMA 16x16x32. W_hh: 13 k-tiles in regs (208 VGPR) + 3 k-tiles
// in LDS (B-frag lane-seq, 96 KB). h ping-pong in LDS (2x16 KB) -> ONE raw
// lgkm-only barrier per step; all store/FC work pre-barrier on own data.
// L1 FC = in-register partial dot + global partials + tiny epilogue kernel.
// ---------------------------------------------------------------------------

typedef _Float16 half8 __attribute__((ext_vector_type(8)));
typedef _Float16 half4 __attribute__((ext_vector_type(4)));
typedef float    f32x4 __attribute__((ext_vector_type(4)));

#define T_DIM 512
#define H_DIM 512
#define B_DIM 64

#define RAW_BARRIER() asm volatile("s_waitcnt lgkmcnt(0)\n\ts_barrier" ::: "memory")

__global__ __launch_bounds__(256) void conv_w_f16(
    const float* __restrict__ in, _Float16* __restrict__ out)
{
    int i = (blockIdx.x * 256 + threadIdx.x) * 4;
    float4 v = *(const float4*)(in + i);
    out[i + 0] = (_Float16)v.x;
    out[i + 1] = (_Float16)v.y;
    out[i + 2] = (_Float16)v.z;
    out[i + 3] = (_Float16)v.w;
}

// ---------------------------------------------------------------------------
// Projection GEMM (unchanged from round 6). AMODE 0: A fp32 [B][T][Kin];
// AMODE 1: A fp16 A-seq [g][t][kt][qa*16+m][8]. Out: fp16 frag-packed xw.
// ---------------------------------------------------------------------------
template <int AMODE>
__global__ __launch_bounds__(256) void gemm_proj(
    const float* __restrict__ A32,
    const _Float16* __restrict__ A16,
    const float* __restrict__ W,
    const float* __restrict__ b1,
    const float* __restrict__ b2,
    _Float16* __restrict__ xwF,
    int Kin)
{
    __shared__ float As[16][68];
    __shared__ float Bs[16][68];

    const int tx = threadIdx.x & 15;
    const int ty = threadIdx.x >> 4;
    const int t  = blockIdx.x;
    const int n0 = blockIdx.y * 64;

    float acc[4][4] = {};
    const int rr  = threadIdx.x >> 2;        // 0..63 = batch b
    const int kk4 = (threadIdx.x & 3) * 4;

    for (int kc = 0; kc < Kin; kc += 16) {
        if (AMODE == 0) {
            float4 av = *(const float4*)(A32 + (size_t)(rr * T_DIM + t) * Kin + kc + kk4);
            As[kk4 + 0][rr] = av.x; As[kk4 + 1][rr] = av.y;
            As[kk4 + 2][rr] = av.z; As[kk4 + 3][rr] = av.w;
        } else {
            int g = rr >> 4, m = rr & 15;
            int k = kc + kk4;
            int kt = k >> 5, qa = (k >> 3) & 3, jj = k & 7;
            half4 av = *(const half4*)(
                A16 + ((size_t)(g * T_DIM + t) * 16 + kt) * 512 + (qa * 16 + m) * 8 + jj);
            As[kk4 + 0][rr] = (float)av[0]; As[kk4 + 1][rr] = (float)av[1];
            As[kk4 + 2][rr] = (float)av[2]; As[kk4 + 3][rr] = (float)av[3];
        }
        {
            float4 wv = *(const float4*)(W + (size_t)(n0 + rr) * Kin + kc + kk4);
            Bs[kk4 + 0][rr] = wv.x; Bs[kk4 + 1][rr] = wv.y;
            Bs[kk4 + 2][rr] = wv.z; Bs[kk4 + 3][rr] = wv.w;
        }
        __syncthreads();
#pragma unroll
        for (int kk = 0; kk < 16; ++kk) {
            float4 av = *(const float4*)&As[kk][ty * 4];
            float4 bv = *(const float4*)&Bs[kk][tx * 4];
            float a[4] = {av.x, av.y, av.z, av.w};
            float b[4] = {bv.x, bv.y, bv.z, bv.w};
#pragma unroll
            for (int i = 0; i < 4; ++i)
#pragma unroll
                for (int j = 0; j < 4; ++j)
                    acc[i][j] = fmaf(a[i], b[j], acc[i][j]);
        }
        __syncthreads();
    }

#pragma unroll
    for (int j = 0; j < 4; ++j) {
        int n = n0 + tx * 4 + j;
        float bias = b1[n] + b2[n];
        half4 hv;
#pragma unroll
        for (int i = 0; i < 4; ++i) hv[i] = (_Float16)(acc[i][j] + bias);
        size_t addr = ((size_t)t * 4 + (ty >> 2)) * 8192
                    + ((size_t)blockIdx.y * 4 + (tx >> 2)) * 256
                    + (ty & 3) * 64 + ((tx & 3) * 4 + j) * 4;
        *(half4*)&xwF[addr] = hv;
    }
}

// ---------------------------------------------------------------------------
// Persistent MFMA scan. grid=4, 512 thr (8 waves). Wave w owns n in
// [w*64, w*64+64). wreg: k-tiles 0..12 (208 VGPR). WlB (96 KB): k-tiles
// 13..15 B-frag lane-seq. hA[2] ping-pong (2x16 KB). One barrier/step.
// LAYER 0: h -> h0A (A-seq, pre-barrier own-region readback).
// LAYER 1: in-register FC partials -> part[w][g][t][m] (f32x4 stores).
// ---------------------------------------------------------------------------
template <int LAYER>
__global__ __launch_bounds__(512, 2) void rnn_scan_mfma(
    const _Float16* __restrict__ xwF,   // frag-packed [t][g][8192]
    const _Float16* __restrict__ W16,   // [512][512] fp16
    _Float16* __restrict__ h0A,         // L0 out: A-seq [g][t][kt][lane][8]
    const float* __restrict__ wfc,      // L1: [512] fp32
    float* __restrict__ part)           // L1: [8][4][512][16] fp32 partials
{
    __shared__ _Float16 WlB[3 * 32 * 512];   // 96 KB
    __shared__ _Float16 hA[2][8192];         // 2 x 16 KB ping-pong

    const int tid  = threadIdx.x;
    const int w    = tid >> 6;
    const int lane = tid & 63;
    const int col  = lane & 15;
    const int q    = lane >> 4;
    const int g    = blockIdx.x;

    // zero both h buffers
    {
        half8 z = {};
        half8* p = (half8*)&hA[0][0];
        for (int i = tid; i < 2048; i += 512) p[i] = z;
    }
    // WlB: k-tiles 13..15, B-frag lane-sequential
#pragma unroll
    for (int kt = 0; kt < 3; ++kt)
#pragma unroll
        for (int nt = 0; nt < 4; ++nt)
            *(half8*)&WlB[((kt * 32 + w * 4 + nt) * 512) + lane * 8] =
                *(const half8*)(W16 + (size_t)(w * 64 + nt * 16 + col) * 512
                                + (13 + kt) * 32 + q * 8);
    // wreg: k-tiles 0..12
    half8 wreg[13][4];
#pragma unroll
    for (int kt = 0; kt < 13; ++kt)
#pragma unroll
        for (int nt = 0; nt < 4; ++nt)
            wreg[kt][nt] = *(const half8*)(
                W16 + (size_t)(w * 64 + nt * 16 + col) * 512 + kt * 32 + q * 8);

    // FC weights (layer 1): lane's 4 owned columns
    float wfn[4] = {};
    if (LAYER == 1) {
#pragma unroll
        for (int nt = 0; nt < 4; ++nt) wfn[nt] = wfc[w * 64 + nt * 16 + col];
    }

    __syncthreads();

    int cur = 0;
    for (int t = 0; t < T_DIM; ++t) {
        // xw for this step (frag-packed, one half4 per nt); global latency
        // hides under the MFMA loop (use is at the epilogue add).
        half4 xv[4];
        {
            const _Float16* xwp = xwF + ((size_t)t * 4 + g) * 8192;
#pragma unroll
            for (int nt = 0; nt < 4; ++nt)
                xv[nt] = *(const half4*)(xwp + (w * 4 + nt) * 256 + q * 64 + col * 4);
        }

        f32x4 acc[4] = {};
#pragma unroll
        for (int kt = 0; kt < 16; ++kt) {
            half8 a = *(const half8*)&hA[cur][(kt * 64 + lane) * 8];
#pragma unroll
            for (int nt = 0; nt < 4; ++nt) {
                half8 b;
                if (kt < 13) b = wreg[kt][nt];
                else b = *(const half8*)&WlB[(((kt - 13) * 32 + w * 4 + nt) * 512)
                                             + lane * 8];
                acc[nt] = __builtin_amdgcn_mfma_f32_16x16x32_f16(a, b, acc[nt], 0, 0, 0);
            }
        }

        const int nxt = cur ^ 1;
        float v[4][4];
#pragma unroll
        for (int nt = 0; nt < 4; ++nt) {
            int nn = nt * 16 + col;
            int kt_a = 2 * w + (nn >> 5);
            int qa   = (nn >> 3) & 3;
            int jj   = nn & 7;
#pragma unroll
            for (int r = 0; r < 4; ++r) {
                float vv = fmaxf(acc[nt][r] + (float)xv[nt][r], 0.f);
                v[nt][r] = vv;
                hA[nxt][(kt_a * 64 + qa * 16 + q * 4 + r) * 8 + jj] = (_Float16)vv;
            }
        }

        if (LAYER == 0) {
            // own-region readback (in-order DS per wave) -> coalesced store
#pragma unroll
            for (int e = 0; e < 2; ++e) {
                half8 hv = *(const half8*)&hA[nxt][((w * 2 + e) * 64 + lane) * 8];
                *(half8*)(h0A + ((size_t)(g * T_DIM + t) * 16 + w * 2 + e) * 512
                          + lane * 8) = hv;
            }
        } else {
            // in-register FC partial over this wave's 64 columns
            float p[4];
#pragma unroll
            for (int r = 0; r < 4; ++r) {
                p[r] = v[0][r] * wfn[0] + v[1][r] * wfn[1]
                     + v[2][r] * wfn[2] + v[3][r] * wfn[3];
#pragma unroll
                for (int s = 1; s < 16; s <<= 1) p[r] += __shfl_xor(p[r], s);
            }
            if (col == 0) {
                f32x4 pv = {p[0], p[1], p[2], p[3]};
                *(f32x4*)(part + ((size_t)(w * 4 + g) * T_DIM + t) * 16 + q * 4) = pv;
            }
        }

        RAW_BARRIER();   // lgkm-only: NXT visible; VMEM stays in flight
        cur = nxt;
    }
}

// ---------------------------------------------------------------------------
// FC epilogue: out[b][t] = sigmoid(sum_w part[w][g][t][m] + bias)
// ---------------------------------------------------------------------------
__global__ __launch_bounds__(256) void fc_epilogue(
    const float* __restrict__ part, const float* __restrict__ bfc,
    float* __restrict__ outp)
{
    int i = blockIdx.x * 256 + threadIdx.x;   // i = b*512 + t
    int b = i >> 9, t = i & 511;
    int g = b >> 4, m = b & 15;
    float s = bfc[0];
#pragma unroll
    for (int w = 0; w < 8; ++w)
        s += part[((size_t)(w * 4 + g) * T_DIM + t) * 16 + m];
    outp[i] = 1.f / (1.f + __expf(-s));
}

// ---------------------------------------------------------------------------
extern "C" void kernel_launch(void* const* d_in, const int* in_sizes, int n_in,
                              void* d_out, int out_size, void* d_ws, size_t ws_size,
                              hipStream_t stream)
{
    const float* x     = (const float*)d_in[0];
    const float* W_ih0 = (const float*)d_in[1];
    const float* W_hh0 = (const float*)d_in[2];
    const float* b_ih0 = (const float*)d_in[3];
    const float* b_hh0 = (const float*)d_in[4];
    const float* W_ih1 = (const float*)d_in[5];
    const float* W_hh1 = (const float*)d_in[6];
    const float* b_ih1 = (const float*)d_in[7];
    const float* b_hh1 = (const float*)d_in[8];
    const float* W_fc  = (const float*)d_in[9];
    const float* b_fc  = (const float*)d_in[10];

    _Float16* xwF   = (_Float16*)d_ws;                         // 33.5 MB
    _Float16* h0A   = xwF + (size_t)T_DIM * 4 * 8192;          // 33.5 MB
    _Float16* W16_0 = h0A + (size_t)4 * T_DIM * 16 * 512;      // 512 KB
    _Float16* W16_1 = W16_0 + (size_t)H_DIM * H_DIM;           // 512 KB
    float*    partf = (float*)(W16_1 + (size_t)H_DIM * H_DIM); // 1 MB

    conv_w_f16<<<256, 256, 0, stream>>>(W_hh0, W16_0);
    conv_w_f16<<<256, 256, 0, stream>>>(W_hh1, W16_1);

    dim3 gp(T_DIM, 8);

    gemm_proj<0><<<gp, 256, 0, stream>>>(x, nullptr, W_ih0, b_ih0, b_hh0, xwF, 256);
    rnn_scan_mfma<0><<<4, 512, 0, stream>>>(xwF, W16_0, h0A, nullptr, nullptr);

    gemm_proj<1><<<gp, 256, 0, stream>>>(nullptr, h0A, W_ih1, b_ih1, b_hh1, xwF, 512);
    rnn_scan_mfma<1><<<4, 512, 0, stream>>>(xwF, W16_1, nullptr, W_fc, partf);

    fc_epilogue<<<(B_DIM * T_DIM) / 256, 256, 0, stream>>>(partf, b_fc, (float*)d_out);
}

// Round 8
// 1776.570 us; speedup vs baseline: 1.8890x; 1.8890x over previous
//
#include <hip/hip_runtime.h>

// ---------------------------------------------------------------------------
// 2-layer ReLU RNN (B=64,T=512,I=256,H=512) + FC(512->1) + sigmoid. fp32 I/O.
// Round 8: cross-layer software pipeline in ONE dispatch (24 blocks):
//   blocks 0-3  : scan0 (round-6 core) -> h0A chunks + release flag0[g]
//   blocks 4-19 : persistent xw1 GEMM (g,s): W_ih1 slice staged in LDS once;
//                 per 16-step chunk: h0A -> xw1 frag-packed; release flag1[g,s]
//   blocks 20-23: scan1 (round-6 core) consuming xw1 chunks; FC partials
// Chunk flags: __hip_atomic RELEASE/ACQUIRE @ AGENT scope (cross-XCD safe).
// ---------------------------------------------------------------------------

typedef _Float16 half8 __attribute__((ext_vector_type(8)));
typedef _Float16 half4 __attribute__((ext_vector_type(4)));
typedef float    f32x4 __attribute__((ext_vector_type(4)));

#define T_DIM 512
#define H_DIM 512
#define B_DIM 64
#define CHUNK 16

#define RAW_BARRIER() asm volatile("s_waitcnt lgkmcnt(0)\n\ts_barrier" ::: "memory")

__global__ __launch_bounds__(256) void conv_w_f16(
    const float* __restrict__ in, _Float16* __restrict__ out)
{
    int i = (blockIdx.x * 256 + threadIdx.x) * 4;
    float4 v = *(const float4*)(in + i);
    out[i + 0] = (_Float16)v.x;
    out[i + 1] = (_Float16)v.y;
    out[i + 2] = (_Float16)v.z;
    out[i + 3] = (_Float16)v.w;
}

__global__ __launch_bounds__(64) void init_flags(int* flags)
{
    flags[threadIdx.x & 31] = 0;
}

// ---------------------------------------------------------------------------
// xw0 projection GEMM (fp32 A), writes frag-packed fp16 xw0.
// ---------------------------------------------------------------------------
__global__ __launch_bounds__(256) void gemm_proj0(
    const float* __restrict__ A32,
    const float* __restrict__ W,
    const float* __restrict__ b1,
    const float* __restrict__ b2,
    _Float16* __restrict__ xwF)
{
    __shared__ float As[16][68];
    __shared__ float Bs[16][68];

    const int tx = threadIdx.x & 15;
    const int ty = threadIdx.x >> 4;
    const int t  = blockIdx.x;
    const int n0 = blockIdx.y * 64;

    float acc[4][4] = {};
    const int rr  = threadIdx.x >> 2;
    const int kk4 = (threadIdx.x & 3) * 4;

    for (int kc = 0; kc < 256; kc += 16) {
        {
            float4 av = *(const float4*)(A32 + (size_t)(rr * T_DIM + t) * 256 + kc + kk4);
            As[kk4 + 0][rr] = av.x; As[kk4 + 1][rr] = av.y;
            As[kk4 + 2][rr] = av.z; As[kk4 + 3][rr] = av.w;
            float4 wv = *(const float4*)(W + (size_t)(n0 + rr) * 256 + kc + kk4);
            Bs[kk4 + 0][rr] = wv.x; Bs[kk4 + 1][rr] = wv.y;
            Bs[kk4 + 2][rr] = wv.z; Bs[kk4 + 3][rr] = wv.w;
        }
        __syncthreads();
#pragma unroll
        for (int kk = 0; kk < 16; ++kk) {
            float4 av = *(const float4*)&As[kk][ty * 4];
            float4 bv = *(const float4*)&Bs[kk][tx * 4];
            float a[4] = {av.x, av.y, av.z, av.w};
            float b[4] = {bv.x, bv.y, bv.z, bv.w};
#pragma unroll
            for (int i = 0; i < 4; ++i)
#pragma unroll
                for (int j = 0; j < 4; ++j)
                    acc[i][j] = fmaf(a[i], b[j], acc[i][j]);
        }
        __syncthreads();
    }

#pragma unroll
    for (int j = 0; j < 4; ++j) {
        int n = n0 + tx * 4 + j;
        float bias = b1[n] + b2[n];
        half4 hv;
#pragma unroll
        for (int i = 0; i < 4; ++i) hv[i] = (_Float16)(acc[i][j] + bias);
        size_t addr = ((size_t)t * 4 + (ty >> 2)) * 8192
                    + ((size_t)blockIdx.y * 4 + (tx >> 2)) * 256
                    + (ty & 3) * 64 + ((tx & 3) * 4 + j) * 4;
        *(half4*)&xwF[addr] = hv;
    }
}

// ---------------------------------------------------------------------------
// Fused pipeline kernel: 24 blocks x 512 threads.
// ---------------------------------------------------------------------------
__global__ __launch_bounds__(512, 2) void pipeline(
    const _Float16* __restrict__ xwF0,  // frag-packed layer-0 xw
    _Float16* __restrict__ xwF1,        // frag-packed layer-1 xw (produced here)
    _Float16* __restrict__ h0A,         // A-seq h0 [g][t][kt][lane][8]
    const _Float16* __restrict__ W16_0, // W_hh0 fp16
    const _Float16* __restrict__ W16_1, // W_hh1 fp16
    const float* __restrict__ Wih1,     // [512][512] fp32
    const float* __restrict__ bih1,
    const float* __restrict__ bhh1,
    const float* __restrict__ wfc,      // [512] fp32
    float* __restrict__ part,           // [8][4][512][16] fp32
    int* __restrict__ flags)            // [0..3]=flag0, [4..19]=flag1
{
    __shared__ _Float16 smem[65536];    // 128 KB, carved per role

    const int bx   = blockIdx.x;
    const int tid  = threadIdx.x;
    const int w    = tid >> 6;
    const int lane = tid & 63;
    const int col  = lane & 15;
    const int q    = lane >> 4;

    int* flag0 = flags;       // [4]
    int* flag1 = flags + 4;   // [16]

    // =======================================================================
    if (bx >= 4 && bx < 20) {
        // ---------------- xw1 GEMM role: (g, s) --------------------------
        const int g = (bx - 4) >> 2;
        const int s = (bx - 4) & 3;
        _Float16* Bls = smem;   // B-frag lane-seq [ (kt*8+nt)*64 + lane ]*8

        // stage W_ih1 slice n in [s*128, s*128+128), fp32 -> fp16
        for (int grp = w; grp < 128; grp += 8) {
            int kt = grp >> 3, nt = grp & 7;
            int n  = s * 128 + nt * 16 + col;
            int k0 = kt * 32 + q * 8;
            float4 a = *(const float4*)(Wih1 + (size_t)n * 512 + k0);
            float4 b = *(const float4*)(Wih1 + (size_t)n * 512 + k0 + 4);
            half8 hv;
            hv[0] = (_Float16)a.x; hv[1] = (_Float16)a.y;
            hv[2] = (_Float16)a.z; hv[3] = (_Float16)a.w;
            hv[4] = (_Float16)b.x; hv[5] = (_Float16)b.y;
            hv[6] = (_Float16)b.z; hv[7] = (_Float16)b.w;
            *(half8*)&Bls[(grp * 64 + lane) * 8] = hv;
        }
        float bias[8];
#pragma unroll
        for (int nt = 0; nt < 8; ++nt) {
            int n = s * 128 + nt * 16 + col;
            bias[nt] = bih1[n] + bhh1[n];
        }
        __syncthreads();

        for (int c = 0; c < T_DIM / CHUNK; ++c) {
            while (__hip_atomic_load(&flag0[g], __ATOMIC_ACQUIRE,
                                     __HIP_MEMORY_SCOPE_AGENT) < c + 1)
                __builtin_amdgcn_s_sleep(2);

#pragma unroll
            for (int i = 0; i < 2; ++i) {
                int t = c * CHUNK + w * 2 + i;
                f32x4 acc[8] = {};
#pragma unroll
                for (int kt = 0; kt < 16; ++kt) {
                    half8 a = *(const half8*)(
                        h0A + ((size_t)(g * T_DIM + t) * 16 + kt) * 512 + lane * 8);
#pragma unroll
                    for (int nt = 0; nt < 8; ++nt) {
                        half8 bfr = *(const half8*)&Bls[((kt * 8 + nt) * 64 + lane) * 8];
                        acc[nt] = __builtin_amdgcn_mfma_f32_16x16x32_f16(
                            a, bfr, acc[nt], 0, 0, 0);
                    }
                }
                _Float16* dst = xwF1 + ((size_t)t * 4 + g) * 8192;
#pragma unroll
                for (int nt = 0; nt < 8; ++nt) {
                    half4 hv;
#pragma unroll
                    for (int r = 0; r < 4; ++r)
                        hv[r] = (_Float16)(acc[nt][r] + bias[nt]);
                    *(half4*)(dst + (s * 8 + nt) * 256 + q * 64 + col * 4) = hv;
                }
            }
            __syncthreads();   // drain vmcnt: all waves' xw1 stores visible
            if (tid == 0)
                __hip_atomic_store(&flag1[g * 4 + s], c + 1, __ATOMIC_RELEASE,
                                   __HIP_MEMORY_SCOPE_AGENT);
        }
        return;
    }

    // =======================================================================
    // scan roles (round-6 core). bx 0-3: layer0 g=bx; bx 20-23: layer1 g=bx-20
    const bool L0 = (bx < 4);
    const int  g  = L0 ? bx : bx - 20;
    const _Float16* W16 = L0 ? W16_0 : W16_1;
    const _Float16* xwF = L0 ? xwF0 : xwF1;

    _Float16* WlB = smem;           // 3 k-tiles B-frag lane-seq: 96 KB
    _Float16* hA  = smem + 49152;   // 16 KB

    // zero h
    {
        half8 z = {};
        half8* p = (half8*)hA;
        for (int i = tid; i < 1024; i += 512) p[i] = z;
    }
    // WlB: k-tiles 13..15
#pragma unroll
    for (int kt = 0; kt < 3; ++kt)
#pragma unroll
        for (int nt = 0; nt < 4; ++nt)
            *(half8*)&WlB[((kt * 32 + w * 4 + nt) * 512) + lane * 8] =
                *(const half8*)(W16 + (size_t)(w * 64 + nt * 16 + col) * 512
                                + (13 + kt) * 32 + q * 8);
    // wreg: k-tiles 0..12
    half8 wreg[13][4];
#pragma unroll
    for (int kt = 0; kt < 13; ++kt)
#pragma unroll
        for (int nt = 0; nt < 4; ++nt)
            wreg[kt][nt] = *(const half8*)(
                W16 + (size_t)(w * 64 + nt * 16 + col) * 512 + kt * 32 + q * 8);

    float wfn[4] = {};
    if (!L0) {
#pragma unroll
        for (int nt = 0; nt < 4; ++nt) wfn[nt] = wfc[w * 64 + nt * 16 + col];
    }

    __syncthreads();

    for (int t = 0; t < T_DIM; ++t) {
        if (!L0 && (t & (CHUNK - 1)) == 0) {
            int need = (t >> 4) + 1;
#pragma unroll
            for (int s4 = 0; s4 < 4; ++s4)
                while (__hip_atomic_load(&flag1[g * 4 + s4], __ATOMIC_ACQUIRE,
                                         __HIP_MEMORY_SCOPE_AGENT) < need)
                    __builtin_amdgcn_s_sleep(2);
        }

        // xw for this step (frag-packed)
        half4 xv[4];
        {
            const _Float16* xwp = xwF + ((size_t)t * 4 + g) * 8192;
#pragma unroll
            for (int nt = 0; nt < 4; ++nt)
                xv[nt] = *(const half4*)(xwp + (w * 4 + nt) * 256 + q * 64 + col * 4);
        }

        f32x4 acc[4] = {};
#pragma unroll
        for (int kt = 0; kt < 16; ++kt) {
            half8 a = *(const half8*)&hA[(kt * 64 + lane) * 8];
#pragma unroll
            for (int nt = 0; nt < 4; ++nt) {
                half8 b;
                if (kt < 13) b = wreg[kt][nt];
                else b = *(const half8*)&WlB[(((kt - 13) * 32 + w * 4 + nt) * 512)
                                             + lane * 8];
                acc[nt] = __builtin_amdgcn_mfma_f32_16x16x32_f16(a, b, acc[nt], 0, 0, 0);
            }
        }
        RAW_BARRIER();   // all A-reads of h_{t-1} done

        float v[4][4];
#pragma unroll
        for (int nt = 0; nt < 4; ++nt) {
            int nn = nt * 16 + col;
            int kt_a = 2 * w + (nn >> 5);
            int qa   = (nn >> 3) & 3;
            int jj   = nn & 7;
#pragma unroll
            for (int r = 0; r < 4; ++r) {
                float vv = fmaxf(acc[nt][r] + (float)xv[nt][r], 0.f);
                v[nt][r] = vv;
                hA[(kt_a * 64 + qa * 16 + q * 4 + r) * 8 + jj] = (_Float16)vv;
            }
        }
        RAW_BARRIER();   // h_t visible

        if (L0) {
            // own-region readback -> h0A global (A-seq)
#pragma unroll
            for (int e = 0; e < 2; ++e) {
                half8 hv = *(const half8*)&hA[((w * 2 + e) * 64 + lane) * 8];
                *(half8*)(h0A + ((size_t)(g * T_DIM + t) * 16 + w * 2 + e) * 512
                          + lane * 8) = hv;
            }
            if ((t & (CHUNK - 1)) == CHUNK - 1) {
                __syncthreads();   // drain vmcnt: chunk's h0A stores visible
                if (tid == 0)
                    __hip_atomic_store(&flag0[g], (t >> 4) + 1, __ATOMIC_RELEASE,
                                       __HIP_MEMORY_SCOPE_AGENT);
            }
        } else {
            float p[4];
#pragma unroll
            for (int r = 0; r < 4; ++r) {
                p[r] = v[0][r] * wfn[0] + v[1][r] * wfn[1]
                     + v[2][r] * wfn[2] + v[3][r] * wfn[3];
#pragma unroll
                for (int s = 1; s < 16; s <<= 1) p[r] += __shfl_xor(p[r], s);
            }
            if (col == 0) {
                f32x4 pv = {p[0], p[1], p[2], p[3]};
                *(f32x4*)(part + ((size_t)(w * 4 + g) * T_DIM + t) * 16 + q * 4) = pv;
            }
        }
    }
}

// ---------------------------------------------------------------------------
__global__ __launch_bounds__(256) void fc_epilogue(
    const float* __restrict__ part, const float* __restrict__ bfc,
    float* __restrict__ outp)
{
    int i = blockIdx.x * 256 + threadIdx.x;   // i = b*512 + t
    int b = i >> 9, t = i & 511;
    int g = b >> 4, m = b & 15;
    float s = bfc[0];
#pragma unroll
    for (int w = 0; w < 8; ++w)
        s += part[((size_t)(w * 4 + g) * T_DIM + t) * 16 + m];
    outp[i] = 1.f / (1.f + __expf(-s));
}

// ---------------------------------------------------------------------------
extern "C" void kernel_launch(void* const* d_in, const int* in_sizes, int n_in,
                              void* d_out, int out_size, void* d_ws, size_t ws_size,
                              hipStream_t stream)
{
    const float* x     = (const float*)d_in[0];
    const float* W_ih0 = (const float*)d_in[1];
    const float* W_hh0 = (const float*)d_in[2];
    const float* b_ih0 = (const float*)d_in[3];
    const float* b_hh0 = (const float*)d_in[4];
    const float* W_ih1 = (const float*)d_in[5];
    const float* W_hh1 = (const float*)d_in[6];
    const float* b_ih1 = (const float*)d_in[7];
    const float* b_hh1 = (const float*)d_in[8];
    const float* W_fc  = (const float*)d_in[9];
    const float* b_fc  = (const float*)d_in[10];

    _Float16* xwF0  = (_Float16*)d_ws;                          // 33.5 MB
    _Float16* xwF1  = xwF0 + (size_t)T_DIM * 4 * 8192;          // 33.5 MB
    _Float16* h0A   = xwF1 + (size_t)T_DIM * 4 * 8192;          // 33.5 MB
    _Float16* W16_0 = h0A + (size_t)4 * T_DIM * 16 * 512;       // 512 KB
    _Float16* W16_1 = W16_0 + (size_t)H_DIM * H_DIM;            // 512 KB
    float*    partf = (float*)(W16_1 + (size_t)H_DIM * H_DIM);  // 1 MB
    int*      flags = (int*)(partf + (size_t)8 * 4 * T_DIM * 16);

    init_flags<<<1, 64, 0, stream>>>(flags);
    conv_w_f16<<<256, 256, 0, stream>>>(W_hh0, W16_0);
    conv_w_f16<<<256, 256, 0, stream>>>(W_hh1, W16_1);

    gemm_proj0<<<dim3(T_DIM, 8), 256, 0, stream>>>(x, W_ih0, b_ih0, b_hh0, xwF0);

    pipeline<<<24, 512, 0, stream>>>(xwF0, xwF1, h0A, W16_0, W16_1,
                                     W_ih1, b_ih1, b_hh1, W_fc, partf, flags);

    fc_epilogue<<<(B_DIM * T_DIM) / 256, 256, 0, stream>>>(partf, b_fc, (float*)d_out);
}

// Round 9
// 1731.580 us; speedup vs baseline: 1.9381x; 1.0260x over previous
//
#include <hip/hip_runtime.h>

// ---------------------------------------------------------------------------
// 2-layer ReLU RNN (B=64,T=512,I=256,H=512) + FC(512->1) + sigmoid. fp32 I/O.
// Round 9: single 40-block pipeline dispatch, 256 thr/block, 1 wave/SIMD
// (512-reg unified VGPR+AGPR budget per wave):
//   blocks  0-15: gemm0 (g,s): xw0 = x@Wih0^T + biases   (W in 256 regs)
//   blocks 16-31: gemm1 (g,s): xw1 = h0@Wih1^T + biases  (W 384 regs + 128KB LDS)
//   blocks 32-35: scan0: 4 waves, wave owns 128 n; W_hh0 384 regs + 128KB LDS
//   blocks 36-39: scan1: same + fused FC partials
// Chunk flags (16 steps): __hip_atomic RELEASE/ACQUIRE @ AGENT scope.
// ---------------------------------------------------------------------------

typedef _Float16 half8 __attribute__((ext_vector_type(8)));
typedef _Float16 half4 __attribute__((ext_vector_type(4)));
typedef float    f32x4 __attribute__((ext_vector_type(4)));

#define T_DIM 512
#define H_DIM 512
#define CHUNK 16

#define RAW_BARRIER() asm volatile("s_waitcnt lgkmcnt(0)\n\ts_barrier" ::: "memory")

__global__ __launch_bounds__(256) void conv_w_f16(
    const float* __restrict__ in, _Float16* __restrict__ out)
{
    int i = (blockIdx.x * 256 + threadIdx.x) * 4;
    float4 v = *(const float4*)(in + i);
    out[i + 0] = (_Float16)v.x;
    out[i + 1] = (_Float16)v.y;
    out[i + 2] = (_Float16)v.z;
    out[i + 3] = (_Float16)v.w;
}

__global__ __launch_bounds__(64) void init_flags(int* flags)
{
    flags[threadIdx.x] = 0;
}

// ---------------------------------------------------------------------------
// One fused pipeline kernel. LDS map (halfs):
//   [0, 65536)        W-stash, per-wave: w*16384 + ((kt4*8+nt)*64+lane)*8
//   [65536, 73856)    hbuf[16][520]
// ---------------------------------------------------------------------------
#define WSTASH 0
#define HBUF   65536

__global__ __launch_bounds__(256, 1) void pipeline(
    const float* __restrict__ x,       // [64][512][256] fp32
    const float* __restrict__ Wih0,    // [512][256] fp32
    const float* __restrict__ bih0,
    const float* __restrict__ bhh0,
    const float* __restrict__ Wih1,    // [512][512] fp32
    const float* __restrict__ bih1,
    const float* __restrict__ bhh1,
    const _Float16* __restrict__ W16_0,// [512][512] fp16 (W_hh0)
    const _Float16* __restrict__ W16_1,// [512][512] fp16 (W_hh1)
    const float* __restrict__ wfc,     // [512] fp32
    _Float16* __restrict__ xwF0,       // frag-packed [t][g][8192]
    _Float16* __restrict__ xwF1,       // frag-packed [t][g][8192]
    _Float16* __restrict__ h0,         // [g][t][m][512] fp16
    float* __restrict__ part,          // [16][512][16] fp32
    int* __restrict__ flags)           // [0..15] xw0, [16..19] h0, [20..35] xw1
{
    __shared__ _Float16 smem[73856];   // 147,712 B

    const int bx   = blockIdx.x;
    const int tid  = threadIdx.x;
    const int w    = tid >> 6;    // wave 0..3
    const int lane = tid & 63;
    const int col  = lane & 15;
    const int q    = lane >> 4;

    int* flag_xw0 = flags;        // [16] (g*4+s)
    int* flag_h0  = flags + 16;   // [4]
    int* flag_xw1 = flags + 20;   // [16] (g*4+s)

    // =======================================================================
    if (bx < 16) {
        // -------- gemm0: xw0[t][m][n] = x[m][:]·Wih0[n][:] + biases --------
        const int g = bx >> 2, s = bx & 3;

        half8 wb[8][8];                    // B-frags Wih0, 256 regs
        float bias[8];
#pragma unroll
        for (int nt = 0; nt < 8; ++nt) {
            int n = w * 128 + nt * 16 + col;
            bias[nt] = bih0[n] + bhh0[n];
#pragma unroll
            for (int kt = 0; kt < 8; ++kt) {
                const float* p = Wih0 + (size_t)n * 256 + kt * 32 + q * 8;
                float4 f0 = *(const float4*)p;
                float4 f1 = *(const float4*)(p + 4);
                half8 hv;
                hv[0]=(_Float16)f0.x; hv[1]=(_Float16)f0.y;
                hv[2]=(_Float16)f0.z; hv[3]=(_Float16)f0.w;
                hv[4]=(_Float16)f1.x; hv[5]=(_Float16)f1.y;
                hv[6]=(_Float16)f1.z; hv[7]=(_Float16)f1.w;
                wb[kt][nt] = hv;
            }
        }

        for (int c = 0; c < T_DIM / CHUNK; ++c) {
#pragma unroll
            for (int i = 0; i < 4; ++i) {
                int t = c * CHUNK + s * 4 + i;
                f32x4 acc[8] = {};
#pragma unroll
                for (int kt = 0; kt < 8; ++kt) {
                    const float* p = x + ((size_t)(g * 16 + col) * T_DIM + t) * 256
                                       + kt * 32 + q * 8;
                    float4 a0 = *(const float4*)p;
                    float4 a1 = *(const float4*)(p + 4);
                    half8 ah;
                    ah[0]=(_Float16)a0.x; ah[1]=(_Float16)a0.y;
                    ah[2]=(_Float16)a0.z; ah[3]=(_Float16)a0.w;
                    ah[4]=(_Float16)a1.x; ah[5]=(_Float16)a1.y;
                    ah[6]=(_Float16)a1.z; ah[7]=(_Float16)a1.w;
#pragma unroll
                    for (int nt = 0; nt < 8; ++nt)
                        acc[nt] = __builtin_amdgcn_mfma_f32_16x16x32_f16(
                            ah, wb[kt][nt], acc[nt], 0, 0, 0);
                }
                _Float16* dst = xwF0 + ((size_t)t * 4 + g) * 8192 + lane * 4;
#pragma unroll
                for (int nt = 0; nt < 8; ++nt) {
                    half4 hv;
#pragma unroll
                    for (int r = 0; r < 4; ++r)
                        hv[r] = (_Float16)(acc[nt][r] + bias[nt]);
                    *(half4*)(dst + (w * 8 + nt) * 256) = hv;
                }
            }
            __syncthreads();   // full drain: xw0 chunk stores visible
            if (tid == 0)
                __hip_atomic_store(&flag_xw0[g * 4 + s], c + 1, __ATOMIC_RELEASE,
                                   __HIP_MEMORY_SCOPE_AGENT);
        }
        return;
    }

    // =======================================================================
    if (bx < 32) {
        // -------- gemm1: xw1 = h0 @ Wih1^T + biases --------
        const int g = (bx - 16) >> 2, s = (bx - 16) & 3;

        half8 wb[12][8];                   // B-frags kt 0..11, 384 regs
        float bias[8];
#pragma unroll
        for (int nt = 0; nt < 8; ++nt) {
            int n = w * 128 + nt * 16 + col;
            bias[nt] = bih1[n] + bhh1[n];
#pragma unroll
            for (int kt = 0; kt < 16; ++kt) {
                const float* p = Wih1 + (size_t)n * 512 + kt * 32 + q * 8;
                float4 f0 = *(const float4*)p;
                float4 f1 = *(const float4*)(p + 4);
                half8 hv;
                hv[0]=(_Float16)f0.x; hv[1]=(_Float16)f0.y;
                hv[2]=(_Float16)f0.z; hv[3]=(_Float16)f0.w;
                hv[4]=(_Float16)f1.x; hv[5]=(_Float16)f1.y;
                hv[6]=(_Float16)f1.z; hv[7]=(_Float16)f1.w;
                if (kt < 12) wb[kt][nt] = hv;
                else *(half8*)&smem[WSTASH + w * 16384
                                    + (((kt - 12) * 8 + nt) * 64 + lane) * 8] = hv;
            }
        }
        __syncthreads();

        for (int c = 0; c < T_DIM / CHUNK; ++c) {
            while (__hip_atomic_load(&flag_h0[g], __ATOMIC_ACQUIRE,
                                     __HIP_MEMORY_SCOPE_AGENT) < c + 1)
                __builtin_amdgcn_s_sleep(2);
#pragma unroll
            for (int i = 0; i < 4; ++i) {
                int t = c * CHUNK + s * 4 + i;
                f32x4 acc[8] = {};
#pragma unroll
                for (int kt = 0; kt < 16; ++kt) {
                    half8 ah = *(const half8*)(
                        h0 + ((size_t)(g * T_DIM + t) * 16 + col) * 512
                           + kt * 32 + q * 8);
#pragma unroll
                    for (int nt = 0; nt < 8; ++nt) {
                        half8 b;
                        if (kt < 12) b = wb[kt][nt];
                        else b = *(const half8*)&smem[WSTASH + w * 16384
                                 + (((kt - 12) * 8 + nt) * 64 + lane) * 8];
                        acc[nt] = __builtin_amdgcn_mfma_f32_16x16x32_f16(
                            ah, b, acc[nt], 0, 0, 0);
                    }
                }
                _Float16* dst = xwF1 + ((size_t)t * 4 + g) * 8192 + lane * 4;
#pragma unroll
                for (int nt = 0; nt < 8; ++nt) {
                    half4 hv;
#pragma unroll
                    for (int r = 0; r < 4; ++r)
                        hv[r] = (_Float16)(acc[nt][r] + bias[nt]);
                    *(half4*)(dst + (w * 8 + nt) * 256) = hv;
                }
            }
            __syncthreads();
            if (tid == 0)
                __hip_atomic_store(&flag_xw1[g * 4 + s], c + 1, __ATOMIC_RELEASE,
                                   __HIP_MEMORY_SCOPE_AGENT);
        }
        return;
    }

    // =======================================================================
    // scan roles: bx 32-35 layer0 (g=bx-32), bx 36-39 layer1 (g=bx-36)
    const bool L0 = (bx < 36);
    const int  g  = L0 ? bx - 32 : bx - 36;
    const _Float16* W16 = L0 ? W16_0 : W16_1;
    const _Float16* xwF = L0 ? xwF0 : xwF1;
    int* waitf = L0 ? flag_xw0 : flag_xw1;

    // zero hbuf
    for (int i = tid; i < 16 * 520; i += 256) smem[HBUF + i] = (_Float16)0.f;

    // W_hh: kt 12..15 -> per-wave LDS stash; kt 0..11 -> registers
#pragma unroll
    for (int kt4 = 0; kt4 < 4; ++kt4)
#pragma unroll
        for (int nt = 0; nt < 8; ++nt)
            *(half8*)&smem[WSTASH + w * 16384 + ((kt4 * 8 + nt) * 64 + lane) * 8] =
                *(const half8*)(W16 + (size_t)(w * 128 + nt * 16 + col) * 512
                                + (12 + kt4) * 32 + q * 8);
    half8 wreg[12][8];
#pragma unroll
    for (int kt = 0; kt < 12; ++kt)
#pragma unroll
        for (int nt = 0; nt < 8; ++nt)
            wreg[kt][nt] = *(const half8*)(
                W16 + (size_t)(w * 128 + nt * 16 + col) * 512 + kt * 32 + q * 8);

    float wfn[8] = {};
    if (!L0) {
#pragma unroll
        for (int nt = 0; nt < 8; ++nt) wfn[nt] = wfc[w * 128 + nt * 16 + col];
    }

    __syncthreads();

    for (int t = 0; t < T_DIM; ++t) {
        if ((t & (CHUNK - 1)) == 0) {
            int need = (t >> 4) + 1;
#pragma unroll
            for (int s4 = 0; s4 < 4; ++s4)
                while (__hip_atomic_load(&waitf[g * 4 + s4], __ATOMIC_ACQUIRE,
                                         __HIP_MEMORY_SCOPE_AGENT) < need)
                    __builtin_amdgcn_s_sleep(2);
        }

        // xw loads (frag-packed, 8B/lane coalesced)
        half4 xv[8];
        {
            const _Float16* xwp = xwF + ((size_t)t * 4 + g) * 8192 + lane * 4;
#pragma unroll
            for (int nt = 0; nt < 8; ++nt)
                xv[nt] = *(const half4*)(xwp + (w * 8 + nt) * 256);
        }

        f32x4 acc[8] = {};
#pragma unroll
        for (int kt = 0; kt < 16; ++kt) {
            half8 a = *(const half8*)&smem[HBUF + col * 520 + kt * 32 + q * 8];
#pragma unroll
            for (int nt = 0; nt < 8; ++nt) {
                half8 b;
                if (kt < 12) b = wreg[kt][nt];
                else b = *(const half8*)&smem[WSTASH + w * 16384
                         + (((kt - 12) * 8 + nt) * 64 + lane) * 8];
                acc[nt] = __builtin_amdgcn_mfma_f32_16x16x32_f16(a, b, acc[nt], 0, 0, 0);
            }
        }
        RAW_BARRIER();   // all reads of h_{t-1} done

        // h_t = relu(acc+xw) -> hbuf ; layer1: FC partial in the same pass
        float p0 = 0.f, p1 = 0.f, p2 = 0.f, p3 = 0.f;
#pragma unroll
        for (int nt = 0; nt < 8; ++nt) {
            int n = w * 128 + nt * 16 + col;
#pragma unroll
            for (int r = 0; r < 4; ++r) {
                float v = fmaxf(acc[nt][r] + (float)xv[nt][r], 0.f);
                smem[HBUF + (q * 4 + r) * 520 + n] = (_Float16)v;
                if (!L0) {
                    float pv = v * wfn[nt];
                    if (r == 0) p0 += pv; else if (r == 1) p1 += pv;
                    else if (r == 2) p2 += pv; else p3 += pv;
                }
            }
        }
        RAW_BARRIER();   // h_t visible

        if (L0) {
            // readback hbuf rows -> h0 [g][t][m][512] (16B coalesced)
            int m = w * 4 + q;
#pragma unroll
            for (int seg = 0; seg < 4; ++seg) {
                half8 hv = *(const half8*)&smem[HBUF + m * 520 + col * 32 + seg * 8];
                *(half8*)(h0 + ((size_t)(g * T_DIM + t) * 16 + m) * 512
                          + col * 32 + seg * 8) = hv;
            }
            if ((t & (CHUNK - 1)) == CHUNK - 1) {
                __syncthreads();   // drain all waves' h0 stores
                if (tid == 0)
                    __hip_atomic_store(&flag_h0[g], (t >> 4) + 1, __ATOMIC_RELEASE,
                                       __HIP_MEMORY_SCOPE_AGENT);
            }
        } else {
            // reduce partials over col lanes (m = q*4+r fixed per r)
#pragma unroll
            for (int s2 = 1; s2 < 16; s2 <<= 1) {
                p0 += __shfl_xor(p0, s2); p1 += __shfl_xor(p1, s2);
                p2 += __shfl_xor(p2, s2); p3 += __shfl_xor(p3, s2);
            }
            if (col == 0) {
                f32x4 pv = {p0, p1, p2, p3};
                *(f32x4*)(part + ((size_t)(g * 4 + w) * T_DIM + t) * 16 + q * 4) = pv;
            }
        }
    }
}

// ---------------------------------------------------------------------------
__global__ __launch_bounds__(256) void fc_epilogue(
    const float* __restrict__ part, const float* __restrict__ bfc,
    float* __restrict__ outp)
{
    int i = blockIdx.x * 256 + threadIdx.x;   // i = b*512 + t
    int b = i >> 9, t = i & 511;
    int g = b >> 4, m = b & 15;
    float s = bfc[0];
#pragma unroll
    for (int w = 0; w < 4; ++w)
        s += part[((size_t)(g * 4 + w) * T_DIM + t) * 16 + m];
    outp[i] = 1.f / (1.f + __expf(-s));
}

// ---------------------------------------------------------------------------
extern "C" void kernel_launch(void* const* d_in, const int* in_sizes, int n_in,
                              void* d_out, int out_size, void* d_ws, size_t ws_size,
                              hipStream_t stream)
{
    const float* x     = (const float*)d_in[0];
    const float* W_ih0 = (const float*)d_in[1];
    const float* W_hh0 = (const float*)d_in[2];
    const float* b_ih0 = (const float*)d_in[3];
    const float* b_hh0 = (const float*)d_in[4];
    const float* W_ih1 = (const float*)d_in[5];
    const float* W_hh1 = (const float*)d_in[6];
    const float* b_ih1 = (const float*)d_in[7];
    const float* b_hh1 = (const float*)d_in[8];
    const float* W_fc  = (const float*)d_in[9];
    const float* b_fc  = (const float*)d_in[10];

    _Float16* xwF0  = (_Float16*)d_ws;                          // 33.5 MB
    _Float16* xwF1  = xwF0 + (size_t)T_DIM * 4 * 8192;          // 33.5 MB
    _Float16* h0    = xwF1 + (size_t)T_DIM * 4 * 8192;          // 33.5 MB
    _Float16* W16_0 = h0 + (size_t)4 * T_DIM * 16 * 512;        // 512 KB
    _Float16* W16_1 = W16_0 + (size_t)H_DIM * H_DIM;            // 512 KB
    float*    partf = (float*)(W16_1 + (size_t)H_DIM * H_DIM);  // 512 KB
    int*      flags = (int*)(partf + (size_t)16 * T_DIM * 16);

    init_flags<<<1, 64, 0, stream>>>(flags);
    conv_w_f16<<<256, 256, 0, stream>>>(W_hh0, W16_0);
    conv_w_f16<<<256, 256, 0, stream>>>(W_hh1, W16_1);

    pipeline<<<40, 256, 0, stream>>>(x, W_ih0, b_ih0, b_hh0,
                                     W_ih1, b_ih1, b_hh1,
                                     W16_0, W16_1, W_fc,
                                     xwF0, xwF1, h0, partf, flags);

    fc_epilogue<<<(64 * T_DIM) / 256, 256, 0, stream>>>(partf, b_fc, (float*)d_out);
}